// Round 5
// baseline (327.167 us; speedup 1.0000x reference)
//
#include <hip/hip_runtime.h>

// Problem constants (from reference)
constexpr int S  = 4096;   // N_SAMPLES
constexpr int W  = 16;     // N_WIDTH
constexpr int NN = 193;    // N_NODES
constexpr int DD = 2;      // NDIM_IN
constexpr int SW = S * W;                  // 65536
constexpr int PHI_OFF = 3 * SW;            // 196608 (after t, dt, ddt)
constexpr int PHI_SZ  = SW * NN * DD;      // 25,296,896 floats per tensor
constexpr long long DX_OFF = (long long)PHI_OFF + 3LL * PHI_SZ;  // 76,087,296

constexpr int ROW_F    = NN * DD;          // 386 floats per (node,dim) row
constexpr int CHUNK_F4 = ROW_F * W / 4;    // 1544 float4 per (tensor,sample) chunk
constexpr long long G4TOT = 3LL * PHI_SZ / 4;  // 18,972,672 float4 groups total

// Pass-2 geometry: fill-like dense sweeping front
constexpr int P2B     = 2048;              // blocks
constexpr int TPB     = 256;               // threads/block
constexpr int STRIDE4 = P2B * TPB;         // 524288 float4 per grid stride (8 MB)
constexpr int DQ = STRIDE4 % CHUNK_F4;     // 872  (in-chunk float4 advance)
constexpr int DI = STRIDE4 / CHUNK_F4;     // 339  (chunk index advance)
constexpr int DM = (4 * DQ) % ROW_F;       // 14   (row-float advance; 4*1544 ≡ 0 mod 386)

// Workspace layout: vals table [a][d][p][i] (i fastest, coalesced), then nl pack
constexpr int VWS_FLOATS = 3 * DD * 4 * S; // 98304 floats = 393216 B
constexpr size_t NWS_OFF = (size_t)VWS_FLOATS * 4;  // byte offset of nl table

typedef float f32x4 __attribute__((ext_vector_type(4)));

// ---------------------------------------------------------------------------
// Pass 1: one thread per sample. Computes the cubic Lagrange basis (values,
// d/dx, d2/dx2) for both input dims, writes the compact tables to workspace,
// the t/dt/ddt dot products, and delta_x. Formulas identical to the
// previously-verified kernel (bit-exact outputs).
// ---------------------------------------------------------------------------
__global__ __launch_bounds__(256)
void kan_pass1(const float* __restrict__ x, const float* __restrict__ w,
               float* __restrict__ out, float* __restrict__ vws,
               unsigned* __restrict__ nws) {
    const int i = blockIdx.x * 256 + threadIdx.x;
    if (i >= S) return;

    float v[3][DD][4];
    int   nl[DD];

#pragma unroll
    for (int d = 0; d < DD; ++d) {
        float xv = x[i * DD + d];
        float xs = 192.0f * xv;                  // (N_NODES-1)*(x-xmin)/(xmax-xmin)
        float fe = floorf(xs / 3.0f);            // element index
        fe = fminf(fmaxf(fe, 0.0f), 63.0f);      // clip to [0, N_ELEMENTS-1]
        int n = (int)(fe * 3.0f);                // left node index
        nl[d] = n;
        float xr = 2.0f * (xs - (float)n) / 3.0f - 1.0f;   // ref coord in [-1,1]

        // Cubic Lagrange basis at nodes {-1,-1/3,1/3,1}
        float xp1 = xr + 1.0f;
        float xm1 = xr - 1.0f;
        float x2  = xr * xr;
        float x2m = x2 - (1.0f / 9.0f);          // (x+1/3)(x-1/3)
        const float c0 = 0.5625f;                // 9/16
        const float c1 = 1.6875f;                // 27/16

        v[0][d][0] = -c0 * x2m * xm1;
        v[0][d][1] =  c1 * xp1 * (xr - (1.0f / 3.0f)) * xm1;
        v[0][d][2] = -c1 * xp1 * (xr + (1.0f / 3.0f)) * xm1;
        v[0][d][3] =  c0 * xp1 * x2m;

        const float idx1 = 128.0f;               // 1/delta_x (exact, 2^7)
        v[1][d][0] = -c0 * (3.0f * x2 - 2.0f * xr - (1.0f / 9.0f)) * idx1;
        v[1][d][1] =  c1 * (3.0f * x2 - (2.0f / 3.0f) * xr - 1.0f) * idx1;
        v[1][d][2] = -c1 * (3.0f * x2 + (2.0f / 3.0f) * xr - 1.0f) * idx1;
        v[1][d][3] =  c0 * (3.0f * x2 + 2.0f * xr - (1.0f / 9.0f)) * idx1;

        const float idx2 = 16384.0f;             // 1/delta_x^2 (exact, 2^14)
        v[2][d][0] = -c0 * (6.0f * xr - 2.0f) * idx2;
        v[2][d][1] =  c1 * (6.0f * xr - (2.0f / 3.0f)) * idx2;
        v[2][d][2] = -c1 * (6.0f * xr + (2.0f / 3.0f)) * idx2;
        v[2][d][3] =  c0 * (6.0f * xr + 2.0f) * idx2;
    }

    nws[i] = (unsigned)nl[0] | ((unsigned)nl[1] << 8);

    // Compact vals table, [a][d][p][i]: coalesced stores (consecutive i contiguous)
#pragma unroll
    for (int a = 0; a < 3; ++a)
#pragma unroll
        for (int d = 0; d < DD; ++d)
#pragma unroll
            for (int p = 0; p < 4; ++p)
                vws[((a * 2 + d) * 4 + p) * S + i] = v[a][d][p];

    // t/dt/ddt dot products; 16 consecutive floats per (a,i) -> float4 stores
#pragma unroll
    for (int a = 0; a < 3; ++a) {
        float s[W];
#pragma unroll
        for (int k = 0; k < W; ++k) {
            float acc = 0.0f;
#pragma unroll
            for (int d = 0; d < DD; ++d) {
                int base = k * ROW_F + nl[d] * DD + d;
#pragma unroll
                for (int p = 0; p < 4; ++p)
                    acc += w[base + p * DD] * v[a][d][p];
            }
            s[k] = acc;
        }
        f32x4* o4 = (f32x4*)(out + (size_t)a * SW + (size_t)i * W);
#pragma unroll
        for (int q = 0; q < 4; ++q)
            o4[q] = (f32x4){s[4 * q], s[4 * q + 1], s[4 * q + 2], s[4 * q + 3]};
    }

    if (i == 0)
        out[DX_OFF] = 0.0078125f;   // delta_x
}

// ---------------------------------------------------------------------------
// Pass 2: fill-shaped streaming store. Pure grid-stride over the 18,972,672
// output float4 groups -> the in-flight store front is one contiguous 8 MB
// region sweeping linearly (same pattern as the 6.25 TB/s harness fill).
// Group g covers floats m..m+3 of the 386-float row of chunk I = g/1544
// (chunks are [tensor a][sample i], a = I>>12, i = I&4095). ~94% of groups
// are exactly zero (only nodes nl..nl+3 are active per dim).
// ---------------------------------------------------------------------------
__global__ __launch_bounds__(256)
void kan_pass2(float* __restrict__ out, const float* __restrict__ vws,
               const unsigned* __restrict__ nws) {
    const int g0 = blockIdx.x * 256 + threadIdx.x;   // < 524288

    unsigned I = (unsigned)g0 / CHUNK_F4;            // chunk index (magic-div)
    unsigned q = (unsigned)g0 - I * CHUNK_F4;        // float4 within chunk
    unsigned m = (q * 4u) % ROW_F;                   // float within row (even)

    f32x4* p4 = (f32x4*)(out + PHI_OFF) + g0;

    for (long long g = g0; g < G4TOT; g += STRIDE4) {
        const unsigned i  = I & (unsigned)(S - 1);   // sample (S = 4096 pow2)
        const unsigned a  = I >> 12;                 // tensor 0..2
        const unsigned pk = nws[i];
        const int n0 = (int)(m >> 1);                          // node of floats x,y
        const int n1 = (m == (unsigned)(ROW_F - 2)) ? 0 : n0 + 1;  // node of z,w (wrap)
        const int nl0 = (int)(pk & 0xFFu);
        const int nl1 = (int)(pk >> 8);

        const unsigned ux = (unsigned)(n0 - nl0);    // local basis index if < 4
        const unsigned uy = (unsigned)(n0 - nl1);
        const unsigned uz = (unsigned)(n1 - nl0);
        const unsigned uw = (unsigned)(n1 - nl1);

        f32x4 v = (f32x4){0.f, 0.f, 0.f, 0.f};
        if ((ux < 4u) | (uy < 4u) | (uz < 4u) | (uw < 4u)) {
            const float* vb = vws + (size_t)a * (8 * S) + i;   // [a][d][p][i]
            if (ux < 4u) v.x = vb[(0 * 4 + (int)ux) * S];
            if (uy < 4u) v.y = vb[(1 * 4 + (int)uy) * S];
            if (uz < 4u) v.z = vb[(0 * 4 + (int)uz) * S];
            if (uw < 4u) v.w = vb[(1 * 4 + (int)uw) * S];
        }
        *p4 = v;

        p4 += STRIDE4;
        q += DQ; I += DI;
        if (q >= (unsigned)CHUNK_F4) { q -= CHUNK_F4; ++I; }
        m += DM;
        if (m >= (unsigned)ROW_F) m -= ROW_F;
    }
}

extern "C" void kernel_launch(void* const* d_in, const int* in_sizes, int n_in,
                              void* d_out, int out_size, void* d_ws, size_t ws_size,
                              hipStream_t stream) {
    const float* x = (const float*)d_in[0];   // (4096, 2) fp32
    const float* w = (const float*)d_in[1];   // (16, 193, 2) fp32
    float* out = (float*)d_out;

    float*    vws = (float*)d_ws;                         // 393216 B
    unsigned* nws = (unsigned*)((char*)d_ws + NWS_OFF);   // 16384 B

    kan_pass1<<<(S + 255) / 256, 256, 0, stream>>>(x, w, out, vws, nws);
    kan_pass2<<<P2B, TPB, 0, stream>>>(out, vws, nws);
}

// Round 6
// 302.470 us; speedup vs baseline: 1.0816x; 1.0816x over previous
//
#include <hip/hip_runtime.h>

// Problem constants (from reference)
constexpr int S  = 4096;   // N_SAMPLES
constexpr int W  = 16;     // N_WIDTH
constexpr int NN = 193;    // N_NODES
constexpr int DD = 2;      // NDIM_IN
constexpr int SW = S * W;                  // 65536
constexpr int PHI_OFF = 3 * SW;            // 196608 (after t, dt, ddt)
constexpr int PHI_SZ  = SW * NN * DD;      // 25,296,896 per tensor
constexpr int DX_OFF  = PHI_OFF + 3 * PHI_SZ;  // 76,087,296

// Row length per (i,k): 193 nodes * 2 dims = 386 floats
constexpr int ROW_F    = NN * DD;          // 386
constexpr int ROW_PAD  = 392;              // 386 + 2 wrap-pad, rounded to /8
constexpr int CHUNK_F  = W * ROW_F;        // 6176 floats per (i, tensor)
constexpr int CHUNK_F4 = CHUNK_F / 4;      // 1544 float4 per (i, tensor)
constexpr int STEP_J   = (4 * 256) % ROW_F; // 252: j-advance per 256-thread stride

// Plain clang vector type (16B store emits global_store_dwordx4).
typedef float f32x4 __attribute__((ext_vector_type(4)));

__global__ __launch_bounds__(256)
void kan_fused_kernel(const float* __restrict__ x,
                      const float* __restrict__ w,
                      float* __restrict__ out) {
    const int i   = blockIdx.x;
    const int tid = threadIdx.x;

    // LDS: one padded row per output tensor (phi/dphi/ddphi). Entries
    // [386],[387] replicate [0],[1] so a 16B output group starting at any
    // even j reads 4 contiguous floats with no wrap branch.
    __shared__ __align__(16) float row[3][ROW_PAD];   // 4704 B
    __shared__ float vals[3][DD][4];
    __shared__ int   nls[DD];

    // Phase 1a: zero the rows (incl. pad): 3*392/4 = 294 float4
    {
        f32x4* rz = (f32x4*)&row[0][0];
        for (int idx = tid; idx < (3 * ROW_PAD) / 4; idx += 256)
            rz[idx] = (f32x4){0.f, 0.f, 0.f, 0.f};
    }

    // Phase 1b: threads 0,1 compute the Lagrange basis for dim d = tid
    if (tid < DD) {
        const int d = tid;
        float xv = x[i * DD + d];
        float xs = 192.0f * xv;                  // (N_NODES-1)*(x-xmin)/(xmax-xmin)
        float fe = floorf(xs / 3.0f);            // element index
        fe = fminf(fmaxf(fe, 0.0f), 63.0f);      // clip to [0, N_ELEMENTS-1]
        int nl = (int)(fe * 3.0f);               // left node index
        nls[d] = nl;
        float xr = 2.0f * (xs - (float)nl) / 3.0f - 1.0f;   // ref coord in [-1,1]

        // Cubic Lagrange basis at nodes {-1,-1/3,1/3,1}
        float xp1 = xr + 1.0f;
        float xm1 = xr - 1.0f;
        float x2  = xr * xr;
        float x2m = x2 - (1.0f / 9.0f);          // (x+1/3)(x-1/3)
        const float c0 = 0.5625f;                // 9/16
        const float c1 = 1.6875f;                // 27/16

        vals[0][d][0] = -c0 * x2m * xm1;
        vals[0][d][1] =  c1 * xp1 * (xr - (1.0f / 3.0f)) * xm1;
        vals[0][d][2] = -c1 * xp1 * (xr + (1.0f / 3.0f)) * xm1;
        vals[0][d][3] =  c0 * xp1 * x2m;

        const float idx1 = 128.0f;               // 1/delta_x (exact, 2^7)
        vals[1][d][0] = -c0 * (3.0f * x2 - 2.0f * xr - (1.0f / 9.0f)) * idx1;
        vals[1][d][1] =  c1 * (3.0f * x2 - (2.0f / 3.0f) * xr - 1.0f) * idx1;
        vals[1][d][2] = -c1 * (3.0f * x2 + (2.0f / 3.0f) * xr - 1.0f) * idx1;
        vals[1][d][3] =  c0 * (3.0f * x2 + 2.0f * xr - (1.0f / 9.0f)) * idx1;

        const float idx2 = 16384.0f;             // 1/delta_x^2 (exact, 2^14)
        vals[2][d][0] = -c0 * (6.0f * xr - 2.0f) * idx2;
        vals[2][d][1] =  c1 * (6.0f * xr - (2.0f / 3.0f)) * idx2;
        vals[2][d][2] = -c1 * (6.0f * xr + (2.0f / 3.0f)) * idx2;
        vals[2][d][3] =  c0 * (6.0f * xr + 2.0f) * idx2;
    }

    __syncthreads();

    // Phase 2a: scatter the 24 nonzero entries into the LDS rows,
    // plus the 6 wrap-pad entries (row[a][386+d] mirrors entry d: node 0, dim d).
    if (tid < 24) {
        int a = tid >> 3;           // tensor 0..2
        int r = tid & 7;
        int d = r >> 2;             // dim 0..1
        int p = r & 3;              // local basis index 0..3
        row[a][(nls[d] + p) * DD + d] = vals[a][d][p];
    } else if (tid < 30) {
        int q = tid - 24;
        int a = q >> 1;             // tensor 0..2
        int d = q & 1;              // dim 0..1
        if (nls[d] == 0)            // entry d nonzero only when left node is 0
            row[a][ROW_F + d] = vals[a][d][0];
    }

    // Phase 2b: t/dt/ddt dot products (independent of row[] — only needs vals/nls)
    if (tid < 48) {
        int k = tid / 3;            // width 0..15
        int a = tid % 3;            // tensor 0..2
        float s = 0.0f;
#pragma unroll
        for (int d = 0; d < DD; ++d) {
            int base = k * (NN * DD) + nls[d] * DD + d;
#pragma unroll
            for (int p = 0; p < 4; ++p)
                s += w[base + p * DD] * vals[a][d][p];
        }
        out[a * SW + i * W + k] = s;
    }

    if (i == 0 && tid == 0)
        out[DX_OFF] = 0.0078125f;   // delta_x

    __syncthreads();

    // Phase 3: stream the rows to global, 16 identical copies per tensor.
    // PLAIN float4 stores (global_store_dwordx4, same instruction the 6.25 TB/s
    // harness fill uses). Source float index for output float f is f % 386,
    // maintained incrementally (j += 252 mod 386). j is always even ->
    // 8B-aligned float2 LDS reads; wrap (j=384) reads pad floats [386],[387].
    int j0 = tid * 4;
    if (j0 >= 2 * ROW_F) j0 -= 2 * ROW_F;
    if (j0 >= ROW_F)     j0 -= ROW_F;

#pragma unroll
    for (int a = 0; a < 3; ++a) {
        f32x4* dst = (f32x4*)(out + PHI_OFF + (size_t)a * PHI_SZ
                                  + (size_t)i * CHUNK_F);
        int j  = j0;
        int nn = tid;
#pragma unroll
        for (int it = 0; it < 6; ++it) {        // 6*256 = 1536 of 1544
            float2 u = *(const float2*)&row[a][j];
            float2 v = *(const float2*)&row[a][j + 2];
            dst[nn] = (f32x4){u.x, u.y, v.x, v.y};
            nn += 256;
            j  += STEP_J;
            if (j >= ROW_F) j -= ROW_F;
        }
        if (tid < CHUNK_F4 - 6 * 256) {         // tail: 8 float4, same j chain
            float2 u = *(const float2*)&row[a][j];
            float2 v = *(const float2*)&row[a][j + 2];
            dst[nn] = (f32x4){u.x, u.y, v.x, v.y};
        }
    }
}

extern "C" void kernel_launch(void* const* d_in, const int* in_sizes, int n_in,
                              void* d_out, int out_size, void* d_ws, size_t ws_size,
                              hipStream_t stream) {
    const float* x = (const float*)d_in[0];   // (4096, 2) fp32
    const float* w = (const float*)d_in[1];   // (16, 193, 2) fp32
    float* out = (float*)d_out;

    kan_fused_kernel<<<S, 256, 0, stream>>>(x, w, out);
}